// Round 10
// baseline (31.803 us; speedup 1.0000x reference)
//
#include <hip/hip_runtime.h>
#include <math.h>

#define D_IN 512
#define NQ 4
#define QD 6
#define WPB 4               // waves per block
#define SLOTS 16            // samples per wave (one per grid-stride step)

__device__ __forceinline__ float dot4(float4 a, float4 b) {
    return a.x * b.x + a.y * b.y + a.z * b.z + a.w * b.w;
}

// DPP cross-lane add: v += v_from_lane(perm). VALU-only (no DS pipe).
template <int CTRL>
__device__ __forceinline__ float dpp_add(float v) {
    int s = __builtin_amdgcn_mov_dpp(__float_as_int(v), CTRL, 0xF, 0xF, true);
    return v + __int_as_float(s);
}

// ---------------------------------------------------------------------------
// Fused kernel — grid-strided GEMV edition (DRAM-front compactness probe).
// P1: wave W processes samples {i*nwaves + W, i=0..15}. At step i, ALL 4096
//     waves read the contiguous 8 MB band of rows [i*4096,(i+1)*4096) -- a
//     fill-like compact sliding front instead of 4096 scattered streams.
//     4-deep register window (8 float4 pairs in flight), DPP fold (round-9
//     best), lanes 0..3 write half-angles to per-wave LDS slots.
// P2: wave-autonomous (no __syncthreads, round-8-verified): lanes 0..15 sim
//     slot=lane -> sample lane*nwaves + W, fully-unrolled statevector +
//     post-net, scattered 40B row stores (~4 MB effective, negligible).
// ---------------------------------------------------------------------------
__global__ __launch_bounds__(256, 4) void dqn_fused(
    const float* __restrict__ x,
    const float* __restrict__ pre_w,
    const float* __restrict__ pre_b,
    const float* __restrict__ q_params,
    const float* __restrict__ post_w,
    const float* __restrict__ post_b,
    float* __restrict__ out,
    int nsamp, int nwaves)
{
    __shared__ __align__(16) float ang[WPB][SLOTS][NQ];   // 1 KB

    const int lane = threadIdx.x & 63;
    const int wv   = threadIdx.x >> 6;
    const int W    = blockIdx.x * WPB + wv;   // global wave id

    const float4* xr = reinterpret_cast<const float4*>(x);
    const float4* wr = reinterpret_cast<const float4*>(pre_w);

    // ---------------- P1: grid-strided GEMV ----------------
    float4 wA[4], wB[4];
#pragma unroll
    for (int q = 0; q < 4; ++q) {
        wA[q] = wr[q * (D_IN / 4) + lane];
        wB[q] = wr[q * (D_IN / 4) + 64 + lane];
    }
    const float bias = pre_b[lane & 3];

    // 4-deep load window; indices compile-time after full unroll (rule #20)
    float4 pxa[4], pxb[4];
#pragma unroll
    for (int i = 0; i < 4; ++i) {
        const int s = i * nwaves + W;
        if (s < nsamp) {
            const size_t row = (size_t)s * (D_IN / 4);
            pxa[i] = xr[row + lane];
            pxb[i] = xr[row + 64 + lane];
        }
    }

#pragma unroll
    for (int i = 0; i < SLOTS; ++i) {
        const int s = i * nwaves + W;
        float4 xa = pxa[i & 3], xb = pxb[i & 3];
        // refill window slot with sample i+4 (keeps 4 pairs in flight)
        if (i + 4 < SLOTS) {
            const int s2 = (i + 4) * nwaves + W;
            if (s2 < nsamp) {
                const size_t row2 = (size_t)s2 * (D_IN / 4);
                pxa[i & 3] = xr[row2 + lane];
                pxb[i & 3] = xr[row2 + 64 + lane];
            }
        }
        if (s < nsamp) {
            float a0 = dot4(xa, wA[0]) + dot4(xb, wB[0]);
            float a1 = dot4(xa, wA[1]) + dot4(xb, wB[1]);
            float a2 = dot4(xa, wA[2]) + dot4(xb, wB[2]);
            float a3 = dot4(xa, wA[3]) + dot4(xb, wB[3]);

            // qubit fold within quads (DPP, VALU-only)
            a0 = dpp_add<0xB1>(a0);        // xor1: quad_perm[1,0,3,2]
            a1 = dpp_add<0xB1>(a1);
            a2 = dpp_add<0xB1>(a2);
            a3 = dpp_add<0xB1>(a3);
            float b0 = (lane & 1) ? a1 : a0;
            float b1 = (lane & 1) ? a3 : a2;
            b0 = dpp_add<0x4E>(b0);        // xor2: quad_perm[2,3,0,1]
            b1 = dpp_add<0x4E>(b1);
            float c = (lane & 2) ? b1 : b0;
            c = dpp_add<0x124>(c);         // row_ror:4
            c = dpp_add<0x128>(c);         // row_ror:8
            c += __shfl_xor(c, 16, 64);    // only remaining DS ops
            c += __shfl_xor(c, 32, 64);

            float t = c + bias;
            // tanh(t) = 1 - 2/(e^{2t}+1); __expf inf -> tanh -> 1 (ok)
            float e = __expf(2.0f * t);
            float th = 1.0f - 2.0f / (e + 1.0f);
            if (lane < 4)
                ang[wv][i][lane] = th * 0.78539816339744831f;
        }
    }
    // no __syncthreads(): same-wave LDS dependency only (compiler lgkmcnt)

    // ---------------- P2: sim + post-net (lanes 0..15) ----------------
    if (lane < SLOTS) {
        const int b = lane * nwaves + W;
        if (b < nsamp) {
            float qc[QD][NQ], qs[QD][NQ];
#pragma unroll
            for (int k = 0; k < QD; ++k)
#pragma unroll
                for (int w = 0; w < NQ; ++w)
                    __sincosf(q_params[k * NQ + w] * 0.5f, &qs[k][w], &qc[k][w]);

            float4 ha = *reinterpret_cast<const float4*>(&ang[wv][lane][0]);
            float s0_, c0_, s1_, c1_, s2_, c2_, s3_, c3_;
            __sincosf(ha.x, &s0_, &c0_);
            __sincosf(ha.y, &s1_, &c1_);
            __sincosf(ha.z, &s2_, &c2_);
            __sincosf(ha.w, &s3_, &c3_);

            const float r2 = 0.70710678118654752f;
            float A0[2] = {(c0_ - s0_) * r2, (c0_ + s0_) * r2};
            float A1[2] = {(c1_ - s1_) * r2, (c1_ + s1_) * r2};
            float A2[2] = {(c2_ - s2_) * r2, (c2_ + s2_) * r2};
            float A3[2] = {(c3_ - s3_) * r2, (c3_ + s3_) * r2};

            float u[4], v[4], st[16];
#pragma unroll
            for (int i = 0; i < 4; ++i) { u[i] = A0[i >> 1] * A1[i & 1]; v[i] = A2[i >> 1] * A3[i & 1]; }
#pragma unroll
            for (int i = 0; i < 16; ++i) st[i] = u[i >> 2] * v[i & 3];

#pragma unroll
            for (int k = 0; k < QD; ++k) {
                // CNOT(0,1): b0=1 -> swap b1 (compile-time reg permutation)
#pragma unroll
                for (int j = 0; j < 4; ++j) { float tt = st[8 + j]; st[8 + j] = st[12 + j]; st[12 + j] = tt; }
                // CNOT(2,3): b2=1 -> swap b3
#pragma unroll
                for (int j = 0; j < 4; ++j) { float tt = st[4 * j + 2]; st[4 * j + 2] = st[4 * j + 3]; st[4 * j + 3] = tt; }
                // CNOT(1,2): b1=1 -> swap b2
#pragma unroll
                for (int j = 0; j < 2; ++j)
#pragma unroll
                    for (int d = 0; d < 2; ++d) {
                        const int i0 = j * 8 + 4 + d;
                        float tt = st[i0]; st[i0] = st[i0 + 2]; st[i0 + 2] = tt;
                    }
                // RY on each wire
#pragma unroll
                for (int w = 0; w < NQ; ++w) {
                    const int m = 8 >> w;
                    const float c = qc[k][w], s = qs[k][w];
#pragma unroll
                    for (int i = 0; i < 16; ++i) {
                        if ((i & m) == 0) {
                            float x0 = st[i], x1 = st[i | m];
                            st[i]     = c * x0 - s * x1;
                            st[i | m] = s * x0 + c * x1;
                        }
                    }
                }
            }

            float e0 = 0.f, e1 = 0.f, e2 = 0.f, e3 = 0.f;
#pragma unroll
            for (int i = 0; i < 16; ++i) {
                float p = st[i] * st[i];
                e0 += (i & 8) ? -p : p;
                e1 += (i & 4) ? -p : p;
                e2 += (i & 2) ? -p : p;
                e3 += (i & 1) ? -p : p;
            }

            float r[10];
#pragma unroll
            for (int c = 0; c < 10; ++c) {
                r[c] = post_b[c] + e0 * post_w[c * 4 + 0] + e1 * post_w[c * 4 + 1]
                     + e2 * post_w[c * 4 + 2] + e3 * post_w[c * 4 + 3];
            }
            float2* orow = reinterpret_cast<float2*>(out + (size_t)b * 10);
#pragma unroll
            for (int c = 0; c < 5; ++c)
                orow[c] = make_float2(r[2 * c], r[2 * c + 1]);
        }
    }
}

extern "C" void kernel_launch(void* const* d_in, const int* in_sizes, int n_in,
                              void* d_out, int out_size, void* d_ws, size_t ws_size,
                              hipStream_t stream)
{
    const float* x      = (const float*)d_in[0];
    const float* pre_w  = (const float*)d_in[1];
    const float* pre_b  = (const float*)d_in[2];
    const float* q_par  = (const float*)d_in[3];
    const float* post_w = (const float*)d_in[4];
    const float* post_b = (const float*)d_in[5];
    float* out = (float*)d_out;

    const int nsamp  = in_sizes[0] / D_IN;                     // 65536
    const int blocks = (nsamp + WPB * SLOTS - 1) / (WPB * SLOTS);  // 1024
    const int nwaves = blocks * WPB;                           // 4096

    dqn_fused<<<dim3(blocks), dim3(256), 0, stream>>>(
        x, pre_w, pre_b, q_par, post_w, post_b, out, nsamp, nwaves);
}

// Round 11
// 30.119 us; speedup vs baseline: 1.0559x; 1.0559x over previous
//
#include <hip/hip_runtime.h>
#include <math.h>

#define D_IN 512
#define NQ 4
#define QD 6
#define SPW 16              // samples (rows) per wave
#define WPB 4               // waves per block
#define SPB (SPW * WPB)     // 64 samples per block
#define ROWS 4              // staging slots per wave (rows in flight)

__device__ __forceinline__ float dot4(float4 a, float4 b) {
    return a.x * b.x + a.y * b.y + a.z * b.z + a.w * b.w;
}

// DPP cross-lane add: v += v_from_lane(perm). VALU-only (no DS pipe).
template <int CTRL>
__device__ __forceinline__ float dpp_add(float v) {
    int s = __builtin_amdgcn_mov_dpp(__float_as_int(v), CTRL, 0xF, 0xF, true);
    return v + __int_as_float(s);
}

template <int N>
__device__ __forceinline__ void wait_vm() {
    if constexpr (N == 0) asm volatile("s_waitcnt vmcnt(0)" ::: "memory");
    else if constexpr (N == 2) asm volatile("s_waitcnt vmcnt(2)" ::: "memory");
    else if constexpr (N == 4) asm volatile("s_waitcnt vmcnt(4)" ::: "memory");
    else asm volatile("s_waitcnt vmcnt(6)" ::: "memory");
}

// Stage 1 KB (64 lanes x 16 B) global -> LDS. gsrc is per-lane (base+lane*4
// floats); LDS dest is wave-uniform base, HW adds lane*16.
__device__ __forceinline__ void stage1k(const float* g, float* l) {
    __builtin_amdgcn_global_load_lds(
        (const __attribute__((address_space(1))) void*)g,
        (__attribute__((address_space(3))) void*)l,
        16, 0, 0);
}

// ---------------------------------------------------------------------------
// Fused kernel — global_load_lds steady-queue edition.
// P1: per wave, a 4-row-deep LDS staging queue. Loads cost zero VGPRs, so the
//     wave re-issues row r+4 immediately after consuming row r: the HBM
//     request stream never gaps (vs the register path's issue-burst/drain
//     duty cycle). Counted vmcnt(6) waits; loads return in-order. Consume =
//     2x ds_read_b128 + DPP fold (round-9 best) + tanh -> ang LDS.
// P2 (threads 0..63 after barrier): fully-unrolled 4-qubit statevector sim +
//     post-net, one sample per thread (round-9 structure).
// ---------------------------------------------------------------------------
__global__ __launch_bounds__(256, 4) void dqn_fused(
    const float* __restrict__ x,
    const float* __restrict__ pre_w,
    const float* __restrict__ pre_b,
    const float* __restrict__ q_params,
    const float* __restrict__ post_w,
    const float* __restrict__ post_b,
    float* __restrict__ out,
    int nsamp)
{
    __shared__ __align__(16) float ang[SPB][NQ];               // 1 KB
    __shared__ __align__(16) float stage[WPB][ROWS][D_IN];     // 32 KB

    const int lane = threadIdx.x & 63;
    const int wv   = threadIdx.x >> 6;
    const int blk0 = blockIdx.x * SPB;
    const int s0   = blk0 + wv * SPW;

    // ---------------- P1: steady-queue GEMV ----------------
    if (s0 + SPW <= nsamp) {
        const float4* wr = reinterpret_cast<const float4*>(pre_w);
        float4 wA[4], wB[4];
#pragma unroll
        for (int q = 0; q < 4; ++q) {
            wA[q] = wr[q * (D_IN / 4) + lane];
            wB[q] = wr[q * (D_IN / 4) + 64 + lane];
        }
        const float bias = pre_b[lane & 3];
        wait_vm<0>();   // drain weight loads so vmcnt counts staging only

        // prologue: fill the 4-slot queue (8 staging calls)
#pragma unroll
        for (int r = 0; r < ROWS; ++r) {
            const float* g = x + (size_t)(s0 + r) * D_IN + lane * 4;
            float* l = &stage[wv][r][0];
            stage1k(g, l);
            stage1k(g + 256, l + 256);
        }

#pragma unroll
        for (int r = 0; r < SPW; ++r) {
            // in-order returns: need 2(r+1) complete of 2*min(r+4,16) issued
            if (r <= SPW - ROWS) wait_vm<2 * (ROWS - 1)>();   // 6
            else if (r == SPW - 3) wait_vm<4>();
            else if (r == SPW - 2) wait_vm<2>();
            else wait_vm<0>();

            const float4* lp = reinterpret_cast<const float4*>(&stage[wv][r & (ROWS - 1)][0]);
            float4 xa = lp[lane];        // ds_read_b128
            float4 xb = lp[64 + lane];   // ds_read_b128

            float a0 = dot4(xa, wA[0]) + dot4(xb, wB[0]);
            float a1 = dot4(xa, wA[1]) + dot4(xb, wB[1]);
            float a2 = dot4(xa, wA[2]) + dot4(xb, wB[2]);
            float a3 = dot4(xa, wA[3]) + dot4(xb, wB[3]);

            // slot data consumed into VGPRs -> safe to overwrite after lgkm drain
            asm volatile("s_waitcnt lgkmcnt(0)" ::: "memory");
            if (r + ROWS < SPW) {
                const float* g = x + (size_t)(s0 + r + ROWS) * D_IN + lane * 4;
                float* l = &stage[wv][r & (ROWS - 1)][0];
                stage1k(g, l);
                stage1k(g + 256, l + 256);
            }

            // qubit fold within quads (DPP, VALU-only)
            a0 = dpp_add<0xB1>(a0);        // xor1: quad_perm[1,0,3,2]
            a1 = dpp_add<0xB1>(a1);
            a2 = dpp_add<0xB1>(a2);
            a3 = dpp_add<0xB1>(a3);
            float b0 = (lane & 1) ? a1 : a0;
            float b1 = (lane & 1) ? a3 : a2;
            b0 = dpp_add<0x4E>(b0);        // xor2: quad_perm[2,3,0,1]
            b1 = dpp_add<0x4E>(b1);
            float c = (lane & 2) ? b1 : b0;
            c = dpp_add<0x124>(c);         // row_ror:4
            c = dpp_add<0x128>(c);         // row_ror:8
            c += __shfl_xor(c, 16, 64);    // only remaining DS shuffles
            c += __shfl_xor(c, 32, 64);

            float t = c + bias;
            // tanh(t) = 1 - 2/(e^{2t}+1); __expf inf -> tanh -> 1 (ok)
            float e = __expf(2.0f * t);
            float th = 1.0f - 2.0f / (e + 1.0f);
            if (lane < 4)
                ang[wv * SPW + r][lane] = th * 0.78539816339744831f;
        }
    } else if (s0 < nsamp) {
        // tail fallback (not taken at nsamp=65536): simple register path
        const float4* xr = reinterpret_cast<const float4*>(x);
        const float4* wr = reinterpret_cast<const float4*>(pre_w);
        float4 wA[4], wB[4];
#pragma unroll
        for (int q = 0; q < 4; ++q) {
            wA[q] = wr[q * (D_IN / 4) + lane];
            wB[q] = wr[q * (D_IN / 4) + 64 + lane];
        }
        const float bias = pre_b[lane & 3];
        for (int r = 0; r < SPW && s0 + r < nsamp; ++r) {
            const size_t row = (size_t)(s0 + r) * (D_IN / 4);
            float4 xa = xr[row + lane], xb = xr[row + 64 + lane];
            float a0 = dot4(xa, wA[0]) + dot4(xb, wB[0]);
            float a1 = dot4(xa, wA[1]) + dot4(xb, wB[1]);
            float a2 = dot4(xa, wA[2]) + dot4(xb, wB[2]);
            float a3 = dot4(xa, wA[3]) + dot4(xb, wB[3]);
            a0 += __shfl_xor(a0, 1, 64); a1 += __shfl_xor(a1, 1, 64);
            a2 += __shfl_xor(a2, 1, 64); a3 += __shfl_xor(a3, 1, 64);
            float b0 = (lane & 1) ? a1 : a0;
            float b1 = (lane & 1) ? a3 : a2;
            b0 += __shfl_xor(b0, 2, 64); b1 += __shfl_xor(b1, 2, 64);
            float c = (lane & 2) ? b1 : b0;
            c += __shfl_xor(c, 4, 64);  c += __shfl_xor(c, 8, 64);
            c += __shfl_xor(c, 16, 64); c += __shfl_xor(c, 32, 64);
            float t = c + bias;
            float e = __expf(2.0f * t);
            float th = 1.0f - 2.0f / (e + 1.0f);
            if (lane < 4)
                ang[wv * SPW + r][lane] = th * 0.78539816339744831f;
        }
    }
    __syncthreads();

    // ---------------- P2: sim + post-net (threads 0..SPB-1) ----------------
    if (threadIdx.x < SPB) {
        const int t = threadIdx.x;
        const int b = blk0 + t;
        if (b < nsamp) {
            float qc[QD][NQ], qs[QD][NQ];
#pragma unroll
            for (int k = 0; k < QD; ++k)
#pragma unroll
                for (int w = 0; w < NQ; ++w)
                    __sincosf(q_params[k * NQ + w] * 0.5f, &qs[k][w], &qc[k][w]);

            float4 ha = *reinterpret_cast<const float4*>(&ang[t][0]);
            float s0_, c0_, s1_, c1_, s2_, c2_, s3_, c3_;
            __sincosf(ha.x, &s0_, &c0_);
            __sincosf(ha.y, &s1_, &c1_);
            __sincosf(ha.z, &s2_, &c2_);
            __sincosf(ha.w, &s3_, &c3_);

            const float r2 = 0.70710678118654752f;
            float A0[2] = {(c0_ - s0_) * r2, (c0_ + s0_) * r2};
            float A1[2] = {(c1_ - s1_) * r2, (c1_ + s1_) * r2};
            float A2[2] = {(c2_ - s2_) * r2, (c2_ + s2_) * r2};
            float A3[2] = {(c3_ - s3_) * r2, (c3_ + s3_) * r2};

            float u[4], v[4], st[16];
#pragma unroll
            for (int i = 0; i < 4; ++i) { u[i] = A0[i >> 1] * A1[i & 1]; v[i] = A2[i >> 1] * A3[i & 1]; }
#pragma unroll
            for (int i = 0; i < 16; ++i) st[i] = u[i >> 2] * v[i & 3];

#pragma unroll
            for (int k = 0; k < QD; ++k) {
                // CNOT(0,1): b0=1 -> swap b1 (compile-time reg permutation)
#pragma unroll
                for (int j = 0; j < 4; ++j) { float tt = st[8 + j]; st[8 + j] = st[12 + j]; st[12 + j] = tt; }
                // CNOT(2,3): b2=1 -> swap b3
#pragma unroll
                for (int j = 0; j < 4; ++j) { float tt = st[4 * j + 2]; st[4 * j + 2] = st[4 * j + 3]; st[4 * j + 3] = tt; }
                // CNOT(1,2): b1=1 -> swap b2
#pragma unroll
                for (int j = 0; j < 2; ++j)
#pragma unroll
                    for (int d = 0; d < 2; ++d) {
                        const int i0 = j * 8 + 4 + d;
                        float tt = st[i0]; st[i0] = st[i0 + 2]; st[i0 + 2] = tt;
                    }
                // RY on each wire
#pragma unroll
                for (int w = 0; w < NQ; ++w) {
                    const int m = 8 >> w;
                    const float c = qc[k][w], s = qs[k][w];
#pragma unroll
                    for (int i = 0; i < 16; ++i) {
                        if ((i & m) == 0) {
                            float x0 = st[i], x1 = st[i | m];
                            st[i]     = c * x0 - s * x1;
                            st[i | m] = s * x0 + c * x1;
                        }
                    }
                }
            }

            float e0 = 0.f, e1 = 0.f, e2 = 0.f, e3 = 0.f;
#pragma unroll
            for (int i = 0; i < 16; ++i) {
                float p = st[i] * st[i];
                e0 += (i & 8) ? -p : p;
                e1 += (i & 4) ? -p : p;
                e2 += (i & 2) ? -p : p;
                e3 += (i & 1) ? -p : p;
            }

            float r[10];
#pragma unroll
            for (int c = 0; c < 10; ++c) {
                r[c] = post_b[c] + e0 * post_w[c * 4 + 0] + e1 * post_w[c * 4 + 1]
                     + e2 * post_w[c * 4 + 2] + e3 * post_w[c * 4 + 3];
            }
            float2* orow = reinterpret_cast<float2*>(out + (size_t)b * 10);
#pragma unroll
            for (int c = 0; c < 5; ++c)
                orow[c] = make_float2(r[2 * c], r[2 * c + 1]);
        }
    }
}

extern "C" void kernel_launch(void* const* d_in, const int* in_sizes, int n_in,
                              void* d_out, int out_size, void* d_ws, size_t ws_size,
                              hipStream_t stream)
{
    const float* x      = (const float*)d_in[0];
    const float* pre_w  = (const float*)d_in[1];
    const float* pre_b  = (const float*)d_in[2];
    const float* q_par  = (const float*)d_in[3];
    const float* post_w = (const float*)d_in[4];
    const float* post_b = (const float*)d_in[5];
    float* out = (float*)d_out;

    const int nsamp = in_sizes[0] / D_IN;              // 65536
    dim3 blk(256);
    dim3 grid((nsamp + SPB - 1) / SPB);                // 1024 blocks
    dqn_fused<<<grid, blk, 0, stream>>>(x, pre_w, pre_b, q_par, post_w, post_b, out, nsamp);
}

// Round 12
// 28.687 us; speedup vs baseline: 1.1086x; 1.0499x over previous
//
#include <hip/hip_runtime.h>
#include <math.h>

#define D_IN 512
#define NQ 4
#define QD 6
#define SPW 16              // samples per wave (GEMV phase)
#define WPB 4               // waves per block
#define SPB (SPW * WPB)     // 64 samples per block

__device__ __forceinline__ float dot4(float4 a, float4 b) {
    return a.x * b.x + a.y * b.y + a.z * b.z + a.w * b.w;
}

// DPP cross-lane add: v += v_from_lane(perm). VALU-only (no DS pipe).
// ctrl: quad_perm -> 0x00-0xFF, row_ror:N -> 0x120+N (rows of 16).
template <int CTRL>
__device__ __forceinline__ float dpp_add(float v) {
    int s = __builtin_amdgcn_mov_dpp(__float_as_int(v), CTRL, 0xF, 0xF, true);
    return v + __int_as_float(s);
}

// ---------------------------------------------------------------------------
// Fused kernel — round-9 champion (28.65 us), restored.
// Phase 1 (all 4 waves): pre-net GEMV + tanh, 16 samples/wave in 2 chunks of
//   8 (16 float4 loads in flight), weights in registers. DPP fold
//   (quad_perm xor1/xor2, row_ror 4/8) -> only 2 DS shuffles per sample.
// Phase 2 (threads 0..63): fully-unrolled 4-qubit statevector sim + post-net,
//   one sample per thread.
// Roofline note: 128 MB compulsory x-read @ ~6.3 TB/s = 20.3 us + ~1 us sim
// tail + ~3-5 us fixed graph/launch overhead => ~25-26 us floor; nine
// structural variants (MFMA, LDS-staging, pipelining, occupancy, barrier
// topology, DRAM-front shaping) all land 28.6-31.8 us.
// ---------------------------------------------------------------------------
__global__ __launch_bounds__(256, 4) void dqn_fused(
    const float* __restrict__ x,
    const float* __restrict__ pre_w,
    const float* __restrict__ pre_b,
    const float* __restrict__ q_params,
    const float* __restrict__ post_w,
    const float* __restrict__ post_b,
    float* __restrict__ out,
    int nsamp)
{
    __shared__ __align__(16) float ang[SPB][NQ];   // half-angles, 1 KB

    const int lane = threadIdx.x & 63;
    const int wv   = threadIdx.x >> 6;
    const int blk0 = blockIdx.x * SPB;

    // ---------------- phase 1: GEMV ----------------
    {
        const int s0 = blk0 + wv * SPW;
        if (s0 < nsamp) {
            const float4* xr = reinterpret_cast<const float4*>(x);
            const float4* wr = reinterpret_cast<const float4*>(pre_w);

            float4 wA[4], wB[4];
#pragma unroll
            for (int q = 0; q < 4; ++q) {
                wA[q] = wr[q * (D_IN / 4) + lane];
                wB[q] = wr[q * (D_IN / 4) + 64 + lane];
            }
            const float bias = pre_b[lane & 3];

#pragma unroll
            for (int ch = 0; ch < SPW / 8; ++ch) {
                // batch-issue 16 float4 loads (8 samples)
                float4 xa[8], xb[8];
#pragma unroll
                for (int j = 0; j < 8; ++j) {
                    const size_t row = (size_t)(s0 + ch * 8 + j) * (D_IN / 4);
                    xa[j] = xr[row + lane];
                    xb[j] = xr[row + 64 + lane];
                }
#pragma unroll
                for (int j = 0; j < 8; ++j) {
                    float a0 = dot4(xa[j], wA[0]) + dot4(xb[j], wB[0]);
                    float a1 = dot4(xa[j], wA[1]) + dot4(xb[j], wB[1]);
                    float a2 = dot4(xa[j], wA[2]) + dot4(xb[j], wB[2]);
                    float a3 = dot4(xa[j], wA[3]) + dot4(xb[j], wB[3]);

                    // qubit fold within quads (DPP, VALU-only)
                    a0 = dpp_add<0xB1>(a0);        // xor1: quad_perm[1,0,3,2]
                    a1 = dpp_add<0xB1>(a1);
                    a2 = dpp_add<0xB1>(a2);
                    a3 = dpp_add<0xB1>(a3);
                    float b0 = (lane & 1) ? a1 : a0;
                    float b1 = (lane & 1) ? a3 : a2;
                    b0 = dpp_add<0x4E>(b0);        // xor2: quad_perm[2,3,0,1]
                    b1 = dpp_add<0x4E>(b1);
                    float c = (lane & 2) ? b1 : b0;
                    // cross-group sum within each row of 16: ror4 + ror8
                    c = dpp_add<0x124>(c);         // row_ror:4
                    c = dpp_add<0x128>(c);         // row_ror:8
                    // across 16-lane rows (only remaining DS ops)
                    c += __shfl_xor(c, 16, 64);
                    c += __shfl_xor(c, 32, 64);

                    float t = c + bias;
                    // tanh(t) = 1 - 2/(e^{2t}+1); __expf inf -> tanh -> 1 (ok)
                    float e = __expf(2.0f * t);
                    float th = 1.0f - 2.0f / (e + 1.0f);
                    if (lane < 4)
                        ang[wv * SPW + ch * 8 + j][lane] = th * 0.78539816339744831f;
                }
            }
        }
    }
    __syncthreads();

    // ---------------- phase 2: sim + post-net (threads 0..SPB-1) ----------------
    if (threadIdx.x < SPB) {
        const int t = threadIdx.x;
        const int b = blk0 + t;
        if (b < nsamp) {
            float qc[QD][NQ], qs[QD][NQ];
#pragma unroll
            for (int k = 0; k < QD; ++k)
#pragma unroll
                for (int w = 0; w < NQ; ++w)
                    __sincosf(q_params[k * NQ + w] * 0.5f, &qs[k][w], &qc[k][w]);

            float4 ha = *reinterpret_cast<const float4*>(&ang[t][0]);
            float s0_, c0_, s1_, c1_, s2_, c2_, s3_, c3_;
            __sincosf(ha.x, &s0_, &c0_);
            __sincosf(ha.y, &s1_, &c1_);
            __sincosf(ha.z, &s2_, &c2_);
            __sincosf(ha.w, &s3_, &c3_);

            const float r2 = 0.70710678118654752f;
            float A0[2] = {(c0_ - s0_) * r2, (c0_ + s0_) * r2};
            float A1[2] = {(c1_ - s1_) * r2, (c1_ + s1_) * r2};
            float A2[2] = {(c2_ - s2_) * r2, (c2_ + s2_) * r2};
            float A3[2] = {(c3_ - s3_) * r2, (c3_ + s3_) * r2};

            float u[4], v[4], st[16];
#pragma unroll
            for (int i = 0; i < 4; ++i) { u[i] = A0[i >> 1] * A1[i & 1]; v[i] = A2[i >> 1] * A3[i & 1]; }
#pragma unroll
            for (int i = 0; i < 16; ++i) st[i] = u[i >> 2] * v[i & 3];

#pragma unroll
            for (int k = 0; k < QD; ++k) {
                // CNOT(0,1): b0=1 -> swap b1 (compile-time reg permutation)
#pragma unroll
                for (int j = 0; j < 4; ++j) { float tt = st[8 + j]; st[8 + j] = st[12 + j]; st[12 + j] = tt; }
                // CNOT(2,3): b2=1 -> swap b3
#pragma unroll
                for (int j = 0; j < 4; ++j) { float tt = st[4 * j + 2]; st[4 * j + 2] = st[4 * j + 3]; st[4 * j + 3] = tt; }
                // CNOT(1,2): b1=1 -> swap b2
#pragma unroll
                for (int j = 0; j < 2; ++j)
#pragma unroll
                    for (int d = 0; d < 2; ++d) {
                        const int i0 = j * 8 + 4 + d;
                        float tt = st[i0]; st[i0] = st[i0 + 2]; st[i0 + 2] = tt;
                    }
                // RY on each wire
#pragma unroll
                for (int w = 0; w < NQ; ++w) {
                    const int m = 8 >> w;
                    const float c = qc[k][w], s = qs[k][w];
#pragma unroll
                    for (int i = 0; i < 16; ++i) {
                        if ((i & m) == 0) {
                            float x0 = st[i], x1 = st[i | m];
                            st[i]     = c * x0 - s * x1;
                            st[i | m] = s * x0 + c * x1;
                        }
                    }
                }
            }

            float e0 = 0.f, e1 = 0.f, e2 = 0.f, e3 = 0.f;
#pragma unroll
            for (int i = 0; i < 16; ++i) {
                float p = st[i] * st[i];
                e0 += (i & 8) ? -p : p;
                e1 += (i & 4) ? -p : p;
                e2 += (i & 2) ? -p : p;
                e3 += (i & 1) ? -p : p;
            }

            float r[10];
#pragma unroll
            for (int c = 0; c < 10; ++c) {
                r[c] = post_b[c] + e0 * post_w[c * 4 + 0] + e1 * post_w[c * 4 + 1]
                     + e2 * post_w[c * 4 + 2] + e3 * post_w[c * 4 + 3];
            }
            float2* orow = reinterpret_cast<float2*>(out + (size_t)b * 10);
#pragma unroll
            for (int c = 0; c < 5; ++c)
                orow[c] = make_float2(r[2 * c], r[2 * c + 1]);
        }
    }
}

extern "C" void kernel_launch(void* const* d_in, const int* in_sizes, int n_in,
                              void* d_out, int out_size, void* d_ws, size_t ws_size,
                              hipStream_t stream)
{
    const float* x      = (const float*)d_in[0];
    const float* pre_w  = (const float*)d_in[1];
    const float* pre_b  = (const float*)d_in[2];
    const float* q_par  = (const float*)d_in[3];
    const float* post_w = (const float*)d_in[4];
    const float* post_b = (const float*)d_in[5];
    float* out = (float*)d_out;

    const int nsamp = in_sizes[0] / D_IN;              // 65536
    dim3 blk(256);
    dim3 grid((nsamp + SPB - 1) / SPB);                // 1024 blocks
    dqn_fused<<<grid, blk, 0, stream>>>(x, pre_w, pre_b, q_par, post_w, post_b, out, nsamp);
}